// Round 5
// baseline (249.129 us; speedup 1.0000x reference)
//
#include <hip/hip_runtime.h>

#define H 1024
#define W 1024
#define K 11
#define RAD 5
#define ROWS 64              /* R0 geometry: best redundancy (74/64=1.16); R1/R4 showed supply */
                             /* and data-volume are not the limiter                            */
#define NIN (ROWS + K - 1)   /* 74 input rows per strip */
#define BW 256               /* columns per block (1 col/thread) */

typedef float v2f __attribute__((ext_vector_type(2)));

__global__ void zero_out_kernel(float* out) {
    if (threadIdx.x == 0) out[0] = 0.0f;
}

__device__ __forceinline__ float4 ld4u(const float* p) {
    float4 v;
    __builtin_memcpy(&v, p, sizeof(float4));
    return v;
}

__device__ __forceinline__ v2f pkfma(v2f a, v2f b, v2f c) {
    return __builtin_elementwise_fma(a, b, c);
}

// Load the 12-float window [col-5, col+7) of both images into SIX NAMED float4s.
// Named scalars (not arrays) so the value can live across the outer-loop backedge
// as SSA phis in VGPRs — arrays there go to scratch (R2 failure mode).
template<bool FAST>
__device__ __forceinline__ void load6(const float* __restrict__ r1,
                                      const float* __restrict__ r2, int col,
                                      float4& a0, float4& a1, float4& a2,
                                      float4& b0, float4& b1, float4& b2) {
    if (FAST) {
        const float* a = r1 + (col - RAD);
        const float* b = r2 + (col - RAD);
        a0 = ld4u(a); a1 = ld4u(a + 4); a2 = ld4u(a + 8);
        b0 = ld4u(b); b1 = ld4u(b + 4); b2 = ld4u(b + 8);
    } else {
        float x[12], y[12];
        #pragma unroll
        for (int m = 0; m < 12; ++m) {
            const int gc = col - RAD + m;
            const bool ok = (unsigned)gc < (unsigned)W;
            x[m] = ok ? r1[gc] : 0.0f;
            y[m] = ok ? r2[gc] : 0.0f;
        }
        a0 = make_float4(x[0], x[1], x[2],  x[3]);
        a1 = make_float4(x[4], x[5], x[6],  x[7]);
        a2 = make_float4(x[8], x[9], x[10], x[11]);
        b0 = make_float4(y[0], y[1], y[2],  y[3]);
        b1 = make_float4(y[4], y[5], y[6],  y[7]);
        b2 = make_float4(y[8], y[9], y[10], y[11]);
    }
}

template<bool FAST>
__device__ __forceinline__ float run_strip(const float* __restrict__ p1,
                                           const float* __restrict__ p2,
                                           int col, int rin0, const float* gw) {
    // Rings: {mu_x,mu_y}, {xx,yy} pairs + scalar xy. 55 floats, static idx (R0-proven).
    v2f  rmu[K], rsq[K];
    float rxy[K];
    float acc = 0.0f;
    const float C1 = 1e-4f;
    const float C2 = 9e-4f;

    // 1-deep software pipeline: next row's loads in flight during current row's
    // compute. This breaks the per-row "load -> vmcnt(0) -> 445-cyc chain" that
    // the counters say costs ~2500 stall cyc/row-step (R1/R4 acquitted supply
    // and data volume).
    float4 na0, na1, na2, nb0, nb1, nb2;
    {
        const int rr0 = min(max(rin0, 0), H - 1);
        load6<FAST>(p1 + (size_t)rr0 * W, p2 + (size_t)rr0 * W, col,
                    na0, na1, na2, nb0, nb1, nb2);
    }

    for (int base = 0; base < NIN; base += K) {
        #pragma unroll
        for (int p = 0; p < K; ++p) {
            const int i = base + p;
            if (i < NIN) {
                // consume the in-flight row (SSA rename, no copies)
                const float4 ca0 = na0, ca1 = na1, ca2 = na2;
                const float4 cb0 = nb0, cb1 = nb1, cb2 = nb2;

                // issue next row's loads (clamped; last one is harmless overfetch)
                {
                    const int rn  = rin0 + i + 1;
                    const int rrn = min(max(rn, 0), H - 1);
                    load6<FAST>(p1 + (size_t)rrn * W, p2 + (size_t)rrn * W, col,
                                na0, na1, na2, nb0, nb1, nb2);
                }

                const int r = rin0 + i;                        // block-uniform
                const float s = ((unsigned)r < (unsigned)H) ? 1.0f : 0.0f;

                const float x[12] = {ca0.x,ca0.y,ca0.z,ca0.w, ca1.x,ca1.y,ca1.z,ca1.w,
                                     ca2.x,ca2.y,ca2.z,ca2.w};
                const float y[12] = {cb0.x,cb0.y,cb0.z,cb0.w, cb1.x,cb1.y,cb1.z,cb1.w,
                                     cb2.x,cb2.y,cb2.z,cb2.w};

                // ---- Horizontal 11-tap, tap-paired packed fp32 (R0 math) ----
                v2f amx = {0.f,0.f}, amy = {0.f,0.f};
                v2f axx = {0.f,0.f}, ayy = {0.f,0.f}, axy = {0.f,0.f};
                #pragma unroll
                for (int e = 0; e < 5; ++e) {
                    v2f w2 = { gw[2*e], gw[2*e+1] };
                    v2f xp = { x[2*e], x[2*e+1] };
                    v2f yp = { y[2*e], y[2*e+1] };
                    v2f wxp = w2 * xp;
                    v2f wyp = w2 * yp;
                    amx += wxp;
                    amy += wyp;
                    axx = pkfma(wxp, xp, axx);
                    ayy = pkfma(wyp, yp, ayy);
                    axy = pkfma(wxp, yp, axy);
                }
                const float twx = gw[10] * x[10];
                const float twy = gw[10] * y[10];
                const float hmx = (amx.x + amx.y) + twx;
                const float hmy = (amy.x + amy.y) + twy;
                const float hxx = fmaf(twx, x[10], axx.x + axx.y);
                const float hyy = fmaf(twy, y[10], ayy.x + ayy.y);
                const float hxy = fmaf(twx, y[10], axy.x + axy.y);

                v2f s2 = { s, s };
                rmu[p] = s2 * (v2f){ hmx, hmy };
                rsq[p] = s2 * (v2f){ hxx, hyy };
                rxy[p] = s * hxy;

                // ---- Vertical 11-tap, plane-paired packed + SSIM ----
                if (i >= K - 1) {
                    v2f mu = {0.f,0.f}, sq = {0.f,0.f};
                    float xy = 0.f;
                    #pragma unroll
                    for (int j = 0; j < K; ++j) {
                        const int sl = (p + 1 + j) % K;        // static after unroll
                        const float w = gw[j];
                        v2f w2 = { w, w };
                        mu = pkfma(w2, rmu[sl], mu);
                        sq = pkfma(w2, rsq[sl], sq);
                        xy = fmaf(w, rxy[sl], xy);
                    }
                    v2f m2 = mu * mu;                          // {mx2, my2}
                    const float mxy  = mu.x * mu.y;
                    v2f sg = sq - m2;                          // {sx2, sy2}
                    const float sxyv = xy - mxy;
                    const float num = fmaf(2.0f, mxy,  C1) * fmaf(2.0f, sxyv, C2);
                    const float den = (m2.x + m2.y + C1) * (sg.x + sg.y + C2);
                    acc += num * __builtin_amdgcn_rcpf(den);
                }
            }
        }
    }
    return acc;
}

__launch_bounds__(256, 3)
__global__ void ssim_kernel(const float* __restrict__ img1,
                            const float* __restrict__ img2,
                            const float* __restrict__ kern,
                            float* __restrict__ out,
                            float inv_n) {
    __shared__ float wsum[4];

    const int tid = threadIdx.x;
    const int col = blockIdx.x * BW + tid;
    const int ry0 = blockIdx.y * ROWS;
    const int b   = blockIdx.z;

    // 1D gaussian = row sums of normalized 2D kernel (exact). Pin to SGPRs.
    float gw[K];
    #pragma unroll
    for (int t = 0; t < K; ++t) {
        float s = 0.0f;
        #pragma unroll
        for (int j = 0; j < K; ++j) s += kern[t * K + j];
        gw[t] = __int_as_float(__builtin_amdgcn_readfirstlane(__float_as_int(s)));
    }

    const float* __restrict__ p1 = img1 + (size_t)b * H * W;
    const float* __restrict__ p2 = img2 + (size_t)b * H * W;
    const int rin0 = ry0 - RAD;

    // Wave-uniform fast/slow split: fast iff ALL lanes' 12-col windows in-bounds.
    const bool colfast = (col >= RAD) && (col + RAD + 1 < W);
    const unsigned long long bal = __ballot(colfast);
    float acc;
    if (bal == ~0ULL) {
        acc = run_strip<true>(p1, p2, col, rin0, gw);
    } else {
        acc = run_strip<false>(p1, p2, col, rin0, gw);
    }

    // Wave butterfly reduce -> cross-wave via LDS -> one atomic per block.
    for (int off = 32; off > 0; off >>= 1)
        acc += __shfl_down(acc, off, 64);
    if ((tid & 63) == 0) wsum[tid >> 6] = acc;
    __syncthreads();
    if (tid == 0) {
        const float s = wsum[0] + wsum[1] + wsum[2] + wsum[3];
        atomicAdd(out, s * inv_n);
    }
}

extern "C" void kernel_launch(void* const* d_in, const int* in_sizes, int n_in,
                              void* d_out, int out_size, void* d_ws, size_t ws_size,
                              hipStream_t stream) {
    const float* img1 = (const float*)d_in[0];
    const float* img2 = (const float*)d_in[1];
    const float* kern = (const float*)d_in[2];
    float* out = (float*)d_out;

    const int B = in_sizes[0] / (H * W);
    const float inv_n = 1.0f / ((float)B * (float)H * (float)W);

    zero_out_kernel<<<dim3(1), dim3(64), 0, stream>>>(out);

    dim3 grid(W / BW, H / ROWS, B);
    ssim_kernel<<<grid, dim3(256), 0, stream>>>(img1, img2, kern, out, inv_n);
}

// Round 6
// 220.913 us; speedup vs baseline: 1.1277x; 1.1277x over previous
//
#include <hip/hip_runtime.h>

#define H 1024
#define W 1024
#define K 11
#define RAD 5
#define ROWS 64              /* R0 geometry: best redundancy (74/64=1.16) */
#define NIN (ROWS + K - 1)   /* 74 input rows per strip */
#define BW 256               /* columns per block (1 col/thread) */

typedef float v2f __attribute__((ext_vector_type(2)));

__global__ void zero_out_kernel(float* out) {
    if (threadIdx.x == 0) out[0] = 0.0f;
}

__device__ __forceinline__ float4 ld4u(const float* p) {
    float4 v;
    __builtin_memcpy(&v, p, sizeof(float4));
    return v;
}

__device__ __forceinline__ v2f pkfma(v2f a, v2f b, v2f c) {
    return __builtin_elementwise_fma(a, b, c);
}

template<bool FAST>
__device__ __forceinline__ void load_row(const float* __restrict__ r1,
                                         const float* __restrict__ r2,
                                         int col, float* x, float* y) {
    if (FAST) {
        const float* a1 = r1 + (col - RAD);
        const float* a2 = r2 + (col - RAD);
        float4 v0 = ld4u(a1), v1 = ld4u(a1 + 4), v2 = ld4u(a1 + 8);
        float4 u0 = ld4u(a2), u1 = ld4u(a2 + 4), u2 = ld4u(a2 + 8);
        x[0]=v0.x; x[1]=v0.y; x[2]=v0.z; x[3]=v0.w;
        x[4]=v1.x; x[5]=v1.y; x[6]=v1.z; x[7]=v1.w;
        x[8]=v2.x; x[9]=v2.y; x[10]=v2.z; x[11]=v2.w;
        y[0]=u0.x; y[1]=u0.y; y[2]=u0.z; y[3]=u0.w;
        y[4]=u1.x; y[5]=u1.y; y[6]=u1.z; y[7]=u1.w;
        y[8]=u2.x; y[9]=u2.y; y[10]=u2.z; y[11]=u2.w;
    } else {
        #pragma unroll
        for (int m = 0; m < 12; ++m) {
            const int gc = col - RAD + m;
            const bool ok = (unsigned)gc < (unsigned)W;
            x[m] = ok ? r1[gc] : 0.0f;
            y[m] = ok ? r2[gc] : 0.0f;
        }
    }
}

/* Vertical tap: slot S at phase P holds the row at distance d=(P-S+11)%11 from
   the newest; its weight is gw[10-d]. P,S are literals -> constant indices. */
#define SSIM_TAP(P,S) do {                                                    \
    const float w = gw[10 - ((P - S + 11) % 11)];                             \
    const v2f w2v = { w, w };                                                 \
    mu = pkfma(w2v, q##S, mu);                                                \
    sq = pkfma(w2v, t##S, sq);                                                \
    xy = fmaf(w, u##S, xy);                                                   \
} while (0)

/* One row-phase: load, horizontal 11-tap, write ring slot P (named regs),
   vertical 11-tap + SSIM when warmed up. All ring state is NAMED variables so
   it crosses the rolled-loop backedge as SSA phis in VGPRs (R2 lesson: arrays
   live across a backedge go to scratch). */
#define SSIM_PHASE(P) do {                                                    \
    const int i = base + P;                                                   \
    if (i < NIN) {                                                            \
        const int r  = rin0 + i;                                              \
        const int rr = min(max(r, 0), H - 1);                                 \
        const float sm = ((unsigned)r < (unsigned)H) ? 1.0f : 0.0f;           \
        float x[12], y[12];                                                   \
        load_row<FAST>(p1 + (size_t)rr * W, p2 + (size_t)rr * W, col, x, y);  \
        v2f amx = {0.f,0.f}, amy = {0.f,0.f};                                 \
        v2f axx = {0.f,0.f}, ayy = {0.f,0.f}, axy = {0.f,0.f};                \
        _Pragma("unroll")                                                     \
        for (int e = 0; e < 5; ++e) {                                         \
            v2f w2 = { gw[2*e], gw[2*e+1] };                                  \
            v2f xp = { x[2*e], x[2*e+1] };                                    \
            v2f yp = { y[2*e], y[2*e+1] };                                    \
            v2f wxp = w2 * xp;                                                \
            v2f wyp = w2 * yp;                                                \
            amx += wxp; amy += wyp;                                           \
            axx = pkfma(wxp, xp, axx);                                        \
            ayy = pkfma(wyp, yp, ayy);                                        \
            axy = pkfma(wxp, yp, axy);                                        \
        }                                                                     \
        const float twx = gw[10] * x[10];                                     \
        const float twy = gw[10] * y[10];                                     \
        const float hmx = (amx.x + amx.y) + twx;                              \
        const float hmy = (amy.x + amy.y) + twy;                              \
        const float hxx = fmaf(twx, x[10], axx.x + axx.y);                    \
        const float hyy = fmaf(twy, y[10], ayy.x + ayy.y);                    \
        const float hxy = fmaf(twx, y[10], axy.x + axy.y);                    \
        const v2f sv = { sm, sm };                                            \
        q##P = sv * (v2f){ hmx, hmy };                                        \
        t##P = sv * (v2f){ hxx, hyy };                                        \
        u##P = sm * hxy;                                                      \
        if (i >= K - 1) {                                                     \
            v2f mu = {0.f,0.f}, sq = {0.f,0.f}; float xy = 0.f;               \
            SSIM_TAP(P,0); SSIM_TAP(P,1); SSIM_TAP(P,2); SSIM_TAP(P,3);       \
            SSIM_TAP(P,4); SSIM_TAP(P,5); SSIM_TAP(P,6); SSIM_TAP(P,7);       \
            SSIM_TAP(P,8); SSIM_TAP(P,9); SSIM_TAP(P,10);                     \
            const v2f m2 = mu * mu;                                           \
            const float mxy  = mu.x * mu.y;                                   \
            const v2f sg = sq - m2;                                           \
            const float sxyv = xy - mxy;                                      \
            const float num = fmaf(2.0f, mxy,  C1) * fmaf(2.0f, sxyv, C2);    \
            const float den = (m2.x + m2.y + C1) * (sg.x + sg.y + C2);        \
            acc += num * __builtin_amdgcn_rcpf(den);                          \
        }                                                                     \
    }                                                                         \
} while (0)

template<bool FAST>
__device__ __forceinline__ float run_strip(const float* __restrict__ p1,
                                           const float* __restrict__ p2,
                                           int col, int rin0, const float* gw) {
    // Ring in 33 NAMED registers (no arrays -> no scratch across the backedge).
    const v2f z2 = {0.f, 0.f};
    v2f q0=z2,q1=z2,q2=z2,q3=z2,q4=z2,q5=z2,q6=z2,q7=z2,q8=z2,q9=z2,q10=z2;
    v2f t0=z2,t1=z2,t2=z2,t3=z2,t4=z2,t5=z2,t6=z2,t7=z2,t8=z2,t9=z2,t10=z2;
    float u0=0,u1=0,u2=0,u3=0,u4=0,u5=0,u6=0,u7=0,u8=0,u9=0,u10=0;
    float acc = 0.0f;
    const float C1 = 1e-4f;
    const float C2 = 9e-4f;

    // ROLLED outer loop: hot body = one 11-phase block (~11 KB), I$-resident,
    // reused 7x per wave and shared by all waves on the CU. The fully-unrolled
    // 74-step body (~60-100 KB) thrashed the 32 KiB I$ — the theory for the
    // invariant ~40% issue efficiency across R0/R1/R4/R5.
    #pragma unroll 1
    for (int it = 0; it < 7; ++it) {
        const int base = it * K;
        SSIM_PHASE(0);  SSIM_PHASE(1);  SSIM_PHASE(2);  SSIM_PHASE(3);
        SSIM_PHASE(4);  SSIM_PHASE(5);  SSIM_PHASE(6);  SSIM_PHASE(7);
        SSIM_PHASE(8);  SSIM_PHASE(9);  SSIM_PHASE(10);
    }
    return acc;
}

__launch_bounds__(256, 2)
__global__ void ssim_kernel(const float* __restrict__ img1,
                            const float* __restrict__ img2,
                            const float* __restrict__ kern,
                            float* __restrict__ out,
                            float inv_n) {
    __shared__ float wsum[4];

    const int tid = threadIdx.x;
    const int col = blockIdx.x * BW + tid;
    const int ry0 = blockIdx.y * ROWS;
    const int b   = blockIdx.z;

    // 1D gaussian = row sums of normalized 2D kernel (exact). Pin to SGPRs.
    float gw[K];
    #pragma unroll
    for (int t = 0; t < K; ++t) {
        float s = 0.0f;
        #pragma unroll
        for (int j = 0; j < K; ++j) s += kern[t * K + j];
        gw[t] = __int_as_float(__builtin_amdgcn_readfirstlane(__float_as_int(s)));
    }

    const float* __restrict__ p1 = img1 + (size_t)b * H * W;
    const float* __restrict__ p2 = img2 + (size_t)b * H * W;
    const int rin0 = ry0 - RAD;

    // Wave-uniform fast/slow split: fast iff ALL lanes' 12-col windows in-bounds.
    const bool colfast = (col >= RAD) && (col + RAD + 1 < W);
    const unsigned long long bal = __ballot(colfast);
    float acc;
    if (bal == ~0ULL) {
        acc = run_strip<true>(p1, p2, col, rin0, gw);
    } else {
        acc = run_strip<false>(p1, p2, col, rin0, gw);
    }

    // Wave butterfly reduce -> cross-wave via LDS -> one atomic per block.
    for (int off = 32; off > 0; off >>= 1)
        acc += __shfl_down(acc, off, 64);
    if ((tid & 63) == 0) wsum[tid >> 6] = acc;
    __syncthreads();
    if (tid == 0) {
        const float s = wsum[0] + wsum[1] + wsum[2] + wsum[3];
        atomicAdd(out, s * inv_n);
    }
}

extern "C" void kernel_launch(void* const* d_in, const int* in_sizes, int n_in,
                              void* d_out, int out_size, void* d_ws, size_t ws_size,
                              hipStream_t stream) {
    const float* img1 = (const float*)d_in[0];
    const float* img2 = (const float*)d_in[1];
    const float* kern = (const float*)d_in[2];
    float* out = (float*)d_out;

    const int B = in_sizes[0] / (H * W);
    const float inv_n = 1.0f / ((float)B * (float)H * (float)W);

    zero_out_kernel<<<dim3(1), dim3(64), 0, stream>>>(out);

    dim3 grid(W / BW, H / ROWS, B);
    ssim_kernel<<<grid, dim3(256), 0, stream>>>(img1, img2, kern, out, inv_n);
}